// Round 4
// baseline (279.154 us; speedup 1.0000x reference)
//
#include <hip/hip_runtime.h>
#include <cstdint>

typedef unsigned short ushort_t;
typedef __bf16 bf16x8 __attribute__((ext_vector_type(8)));
typedef float f32x4 __attribute__((ext_vector_type(4)));

#define B_ 8
#define T_ 2048
#define D_ 1024
#define M_ (B_ * T_)        // 16384
#define NCHUNK 64
#define CHUNKLEN 32         // 64*32 = 2048 = T_

__device__ __forceinline__ ushort_t f2bf(float f) {
    union { float f; uint32_t u; } v; v.f = f;
    uint32_t u = v.u;
    uint32_t r = (u + 0x7fffu + ((u >> 16) & 1u)) >> 16;
    return (ushort_t)r;
}
__device__ __forceinline__ float bf2f(ushort_t h) {
    union { uint32_t u; float f; } v; v.u = ((uint32_t)h) << 16;
    return v.f;
}

__device__ __forceinline__ void async16(const ushort_t* g, ushort_t* l) {
    __builtin_amdgcn_global_load_lds(
        (const __attribute__((address_space(1))) void*)g,
        (__attribute__((address_space(3))) void*)l, 16, 0, 0);
}

// ---------------- one-shot cast: x + Wq + Wk + Wv -> bf16 ----------------
__global__ __launch_bounds__(256) void cast_all(
    const float* __restrict__ x, const float* __restrict__ wq,
    const float* __restrict__ wk, const float* __restrict__ wv,
    ushort_t* __restrict__ xb, ushort_t* __restrict__ Wb) {
    const int nx4 = M_ * D_ / 4, nw4 = D_ * D_ / 4;
    int i = blockIdx.x * blockDim.x + threadIdx.x;
    const float* src; ushort_t* dstp; int si;
    if (i < nx4) {
        src = x; si = i; dstp = xb + (size_t)i * 4;
    } else {
        int j = i - nx4;
        dstp = Wb + (size_t)j * 4;
        if (j < nw4)          { src = wq; si = j; }
        else if (j < 2 * nw4) { src = wk; si = j - nw4; }
        else                  { src = wv; si = j - 2 * nw4; }
    }
    float4 v = ((const float4*)src)[si];
    ushort4 o;
    o.x = f2bf(v.x); o.y = f2bf(v.y); o.z = f2bf(v.z); o.w = f2bf(v.w);
    *(ushort4*)dstp = o;
}

// ============ Unified QKV GEMM: one dispatch, 1536 blocks ============
// blocks [0,512):   q-mode:  mb = idx&127, n0 = (idx>>7)*256; B0=Wq[n0], B1=Wq[n0+128]
//                   -> qb[.., n0..n0+255] = x@Wq^T + bq (bf16)
// blocks [512,1536): kv-mode: mb = j&127,  n0 = (j>>7)*128;  B0=Wk[n0], B1=Wv[n0]
//                   -> kvb[.., n0..n0+127] = (x@Wk^T+bk)*(x@Wv^T+bv) (bf16)
// Identical K-loop & register profile in both modes; only epilogue diverges
// (wave-uniform branch per block).
__global__ __launch_bounds__(256, 2) void gemm_qkv(
    const ushort_t* __restrict__ xb, const ushort_t* __restrict__ Wq,
    const ushort_t* __restrict__ Wk, const ushort_t* __restrict__ Wv,
    const float* __restrict__ bq, const float* __restrict__ bk,
    const float* __restrict__ bv,
    ushort_t* __restrict__ qb, ushort_t* __restrict__ kvb) {
    __shared__ ushort_t As[128 * 32];
    __shared__ ushort_t B0[128 * 32];
    __shared__ ushort_t B1[128 * 32];

    const int idx = blockIdx.x;
    const bool qmode = idx < 512;
    int mb, n0;
    const ushort_t *W0, *W1;
    if (qmode) {
        mb = idx & 127; n0 = (idx >> 7) * 256;
        W0 = Wq + (size_t)n0 * D_;
        W1 = Wq + (size_t)(n0 + 128) * D_;
    } else {
        const int j = idx - 512;
        mb = j & 127; n0 = (j >> 7) * 128;
        W0 = Wk + (size_t)n0 * D_;
        W1 = Wv + (size_t)n0 * D_;
    }
    const int m0 = mb * 128;

    const int t = threadIdx.x;
    const int lane = t & 63, wv = t >> 6;
    const int wr = (wv >> 1) * 64, wc = (wv & 1) * 64;

    f32x4 acc0[4][4], acc1[4][4];
#pragma unroll
    for (int i = 0; i < 4; ++i)
#pragma unroll
        for (int j = 0; j < 4; ++j) {
            acc0[i][j] = (f32x4){0.f, 0.f, 0.f, 0.f};
            acc1[i][j] = (f32x4){0.f, 0.f, 0.f, 0.f};
        }

    const int r0 = t >> 2, r1 = r0 + 64;
    const int sc = ((t & 3) ^ ((r0 >> 1) & 3)) * 8;   // swizzled source col (elements)

    const int swq = ((lane & 15) >> 1) & 3;
    const int csel = (((lane >> 4) ^ swq)) * 8;       // swizzled LDS col (elements)
    const int rowa = wr + (lane & 15);
    const int rowb = wc + (lane & 15);

    for (int kt = 0; kt < 32; ++kt) {
        const int k0 = kt * 32;
        async16(xb + (size_t)(m0 + r0) * D_ + k0 + sc, &As[t * 8]);
        async16(xb + (size_t)(m0 + r1) * D_ + k0 + sc, &As[(t + 256) * 8]);
        async16(W0 + (size_t)r0 * D_ + k0 + sc, &B0[t * 8]);
        async16(W0 + (size_t)r1 * D_ + k0 + sc, &B0[(t + 256) * 8]);
        async16(W1 + (size_t)r0 * D_ + k0 + sc, &B1[t * 8]);
        async16(W1 + (size_t)r1 * D_ + k0 + sc, &B1[(t + 256) * 8]);
        __syncthreads();

        bf16x8 af[4], b08[4], b18[4];
#pragma unroll
        for (int i = 0; i < 4; ++i)
            af[i] = *(const bf16x8*)&As[(rowa + i * 16) * 32 + csel];
#pragma unroll
        for (int j = 0; j < 4; ++j) {
            b08[j] = *(const bf16x8*)&B0[(rowb + j * 16) * 32 + csel];
            b18[j] = *(const bf16x8*)&B1[(rowb + j * 16) * 32 + csel];
        }
#pragma unroll
        for (int i = 0; i < 4; ++i)
#pragma unroll
            for (int j = 0; j < 4; ++j) {
                acc0[i][j] = __builtin_amdgcn_mfma_f32_16x16x32_bf16(
                    af[i], b08[j], acc0[i][j], 0, 0, 0);
                acc1[i][j] = __builtin_amdgcn_mfma_f32_16x16x32_bf16(
                    af[i], b18[j], acc1[i][j], 0, 0, 0);
            }
        __syncthreads();
    }

    // epilogue: C/D layout col=lane&15, row=(lane>>4)*4+r
    const float* bias0 = qmode ? (bq + n0) : (bk + n0);
    const float* bias1 = qmode ? (bq + n0 + 128) : (bv + n0);
    const int colq = lane & 15;
    const int rowq = (lane >> 4) * 4;
#pragma unroll
    for (int i = 0; i < 4; ++i) {
#pragma unroll
        for (int j = 0; j < 4; ++j) {
            const int c = wc + j * 16 + colq;      // local col within n-tile
            const float bv0 = bias0[c], bv1 = bias1[c];
#pragma unroll
            for (int r = 0; r < 4; ++r) {
                const int rg = m0 + wr + i * 16 + rowq + r;
                if (qmode) {
                    qb[(size_t)rg * D_ + n0 + c]       = f2bf(acc0[i][j][r] + bv0);
                    qb[(size_t)rg * D_ + n0 + 128 + c] = f2bf(acc1[i][j][r] + bv1);
                } else {
                    const float kf = acc0[i][j][r] + bv0;
                    const float vf = acc1[i][j][r] + bv1;
                    kvb[(size_t)rg * D_ + n0 + c] = f2bf(kf * vf);
                }
            }
        }
    }
}

// ---------------- scan pass 1: per-chunk local scan -> chunk sum ----------------
// grid = B_*NCHUNK = 512 blocks; 256 threads x 4 channels = 1024 d.
__global__ __launch_bounds__(256) void scan_chunks(
    const ushort_t* __restrict__ kvb, const float* __restrict__ decay,
    float* __restrict__ S) {
    const int b = blockIdx.x >> 6;
    const int c = blockIdx.x & 63;
    const int d0 = threadIdx.x * 4;
    const float4 dc = *(const float4*)&decay[d0];
    float m0 = 0.f, m1 = 0.f, m2 = 0.f, m3 = 0.f;
    size_t base = ((size_t)b * T_ + c * CHUNKLEN) * D_ + d0;
#pragma unroll 8
    for (int i = 0; i < CHUNKLEN; ++i) {
        ushort4 kv = *(const ushort4*)&kvb[base + (size_t)i * D_];
        m0 = fmaf(dc.x, m0, bf2f(kv.x));
        m1 = fmaf(dc.y, m1, bf2f(kv.y));
        m2 = fmaf(dc.z, m2, bf2f(kv.z));
        m3 = fmaf(dc.w, m3, bf2f(kv.w));
    }
    *(float4*)&S[((size_t)b * NCHUNK + c) * D_ + d0] = make_float4(m0, m1, m2, m3);
}

// ---------------- scan pass 2: carry scan across chunks ----------------
__global__ __launch_bounds__(256) void scan_carry(
    const float* __restrict__ S, const float* __restrict__ decay,
    float* __restrict__ P) {
    const int idx = blockIdx.x * blockDim.x + threadIdx.x;  // 8192
    const int d = idx & (D_ - 1), b = idx >> 10;
    const float dec = decay[d];
    float dL = dec;
    dL *= dL; dL *= dL; dL *= dL; dL *= dL; dL *= dL;  // dec^32
    float p = 0.f;
    for (int c = 0; c < NCHUNK; ++c) {
        const size_t o = ((size_t)b * NCHUNK + c) * D_ + d;
        P[o] = p;
        p = fmaf(dL, p, S[o]);
    }
}

// ---------------- scan pass 3: replay with carry, out = q * mem ----------------
__global__ __launch_bounds__(256) void scan_final(
    const ushort_t* __restrict__ kvb, const ushort_t* __restrict__ qb,
    const float* __restrict__ decay, const float* __restrict__ P,
    float* __restrict__ out) {
    const int b = blockIdx.x >> 6;
    const int c = blockIdx.x & 63;
    const int d0 = threadIdx.x * 4;
    const float4 dc = *(const float4*)&decay[d0];
    const float4 p4 = *(const float4*)&P[((size_t)b * NCHUNK + c) * D_ + d0];
    float m0 = p4.x, m1 = p4.y, m2 = p4.z, m3 = p4.w;
    size_t base = ((size_t)b * T_ + c * CHUNKLEN) * D_ + d0;
#pragma unroll 8
    for (int i = 0; i < CHUNKLEN; ++i) {
        const size_t o = base + (size_t)i * D_;
        ushort4 kv = *(const ushort4*)&kvb[o];
        ushort4 q4 = *(const ushort4*)&qb[o];
        m0 = fmaf(dc.x, m0, bf2f(kv.x));
        m1 = fmaf(dc.y, m1, bf2f(kv.y));
        m2 = fmaf(dc.z, m2, bf2f(kv.z));
        m3 = fmaf(dc.w, m3, bf2f(kv.w));
        *(float4*)&out[o] = make_float4(bf2f(q4.x) * m0, bf2f(q4.y) * m1,
                                        bf2f(q4.z) * m2, bf2f(q4.w) * m3);
    }
}

extern "C" void kernel_launch(void* const* d_in, const int* in_sizes, int n_in,
                              void* d_out, int out_size, void* d_ws, size_t ws_size,
                              hipStream_t stream) {
    const float* x     = (const float*)d_in[0];
    const float* Wq    = (const float*)d_in[1];
    const float* bq    = (const float*)d_in[2];
    const float* Wk    = (const float*)d_in[3];
    const float* bk    = (const float*)d_in[4];
    const float* Wv    = (const float*)d_in[5];
    const float* bv    = (const float*)d_in[6];
    const float* decay = (const float*)d_in[7];
    float* out = (float*)d_out;

    // workspace carve (~107 MB). S/P alias xb (dead after GEMMs).
    char* ws = (char*)d_ws;
    ushort_t* xb  = (ushort_t*)(ws);                        // 33,554,432 B
    ushort_t* Wb  = (ushort_t*)(ws + 33554432);             //  6,291,456 B
    ushort_t* qb  = (ushort_t*)(ws + 39845888);             // 33,554,432 B
    ushort_t* kvb = (ushort_t*)(ws + 73400320);             // 33,554,432 B
    float*    S   = (float*)(ws);                           //  2 MB (aliases xb)
    float*    P   = (float*)(ws + 2097152);                 //  2 MB (aliases xb)

    ushort_t* Wqb = Wb;
    ushort_t* Wkb = Wb + D_ * D_;
    ushort_t* Wvb = Wb + 2 * D_ * D_;

    const int ncast = (M_ * D_ / 4) + (3 * D_ * D_ / 4);
    cast_all<<<ncast / 256, 256, 0, stream>>>(x, Wq, Wk, Wv, xb, Wb);

    gemm_qkv<<<1536, 256, 0, stream>>>(xb, Wqb, Wkb, Wvb, bq, bk, bv, qb, kvb);

    scan_chunks<<<B_ * NCHUNK, 256, 0, stream>>>(kvb, decay, S);
    scan_carry<<<(B_ * D_) / 256, 256, 0, stream>>>(S, decay, P);
    scan_final<<<B_ * NCHUNK, 256, 0, stream>>>(kvb, qb, decay, P, out);
}

// Round 5
// 272.698 us; speedup vs baseline: 1.0237x; 1.0237x over previous
//
#include <hip/hip_runtime.h>
#include <cstdint>

typedef unsigned short ushort_t;
typedef __bf16 bf16x8 __attribute__((ext_vector_type(8)));
typedef float f32x4 __attribute__((ext_vector_type(4)));

#define B_ 8
#define T_ 2048
#define D_ 1024
#define M_ (B_ * T_)        // 16384
#define NCHUNK 64
#define CHUNKLEN 32         // 64*32 = 2048 = T_

__device__ __forceinline__ ushort_t f2bf(float f) {
    union { float f; uint32_t u; } v; v.f = f;
    uint32_t u = v.u;
    uint32_t r = (u + 0x7fffu + ((u >> 16) & 1u)) >> 16;
    return (ushort_t)r;
}
__device__ __forceinline__ float bf2f(ushort_t h) {
    union { uint32_t u; float f; } v; v.u = ((uint32_t)h) << 16;
    return v.f;
}

__device__ __forceinline__ void async16(const ushort_t* g, ushort_t* l) {
    __builtin_amdgcn_global_load_lds(
        (const __attribute__((address_space(1))) void*)g,
        (__attribute__((address_space(3))) void*)l, 16, 0, 0);
}

// ---------------- one-shot cast: x + Wq + Wk + Wv -> bf16 ----------------
__global__ __launch_bounds__(256) void cast_all(
    const float* __restrict__ x, const float* __restrict__ wq,
    const float* __restrict__ wk, const float* __restrict__ wv,
    ushort_t* __restrict__ xb, ushort_t* __restrict__ Wb) {
    const int nx4 = M_ * D_ / 4, nw4 = D_ * D_ / 4;
    int i = blockIdx.x * blockDim.x + threadIdx.x;
    const float* src; ushort_t* dstp; int si;
    if (i < nx4) {
        src = x; si = i; dstp = xb + (size_t)i * 4;
    } else {
        int j = i - nx4;
        dstp = Wb + (size_t)j * 4;
        if (j < nw4)          { src = wq; si = j; }
        else if (j < 2 * nw4) { src = wk; si = j - nw4; }
        else                  { src = wv; si = j - 2 * nw4; }
    }
    float4 v = ((const float4*)src)[si];
    ushort4 o;
    o.x = f2bf(v.x); o.y = f2bf(v.y); o.z = f2bf(v.z); o.w = f2bf(v.w);
    *(ushort4*)dstp = o;
}

// ============ Unified QKV GEMM + fused chunk-scan, one dispatch ============
// blocks [0,512):   q-mode:  mb=idx&127, n0=(idx>>7)*256; qb = x@Wq^T+bq (bf16)
// blocks [512,1536): kv-mode: mb=j&127,  n0=(j>>7)*128;
//   kvb = (x@Wk^T+bk)*(x@Wv^T+bv) (bf16), PLUS chunk-local decay-weighted
//   sums S[b,c,d] = sum_{tau<32} dec_d^(31-tau)*kv[32c+tau,d] computed in
//   registers (each block's 128 rows = exactly 4 chunks of 32 t-steps).
__global__ __launch_bounds__(256, 2) void gemm_qkv(
    const ushort_t* __restrict__ xb, const ushort_t* __restrict__ Wq,
    const ushort_t* __restrict__ Wk, const ushort_t* __restrict__ Wv,
    const float* __restrict__ bq, const float* __restrict__ bk,
    const float* __restrict__ bv, const float* __restrict__ decay,
    ushort_t* __restrict__ qb, ushort_t* __restrict__ kvb,
    float* __restrict__ S) {
    __shared__ ushort_t As[128 * 32];
    __shared__ ushort_t B0[128 * 32];
    __shared__ ushort_t B1[128 * 32];

    const int idx = blockIdx.x;
    const bool qmode = idx < 512;
    int mb, n0;
    const ushort_t *W0, *W1;
    if (qmode) {
        mb = idx & 127; n0 = (idx >> 7) * 256;
        W0 = Wq + (size_t)n0 * D_;
        W1 = Wq + (size_t)(n0 + 128) * D_;
    } else {
        const int j = idx - 512;
        mb = j & 127; n0 = (j >> 7) * 128;
        W0 = Wk + (size_t)n0 * D_;
        W1 = Wv + (size_t)n0 * D_;
    }
    const int m0 = mb * 128;

    const int t = threadIdx.x;
    const int lane = t & 63, wv = t >> 6;
    const int wr = (wv >> 1) * 64, wc = (wv & 1) * 64;

    f32x4 acc0[4][4], acc1[4][4];
#pragma unroll
    for (int i = 0; i < 4; ++i)
#pragma unroll
        for (int j = 0; j < 4; ++j) {
            acc0[i][j] = (f32x4){0.f, 0.f, 0.f, 0.f};
            acc1[i][j] = (f32x4){0.f, 0.f, 0.f, 0.f};
        }

    const int r0 = t >> 2, r1 = r0 + 64;
    const int sc = ((t & 3) ^ ((r0 >> 1) & 3)) * 8;   // swizzled source col

    const int swq = ((lane & 15) >> 1) & 3;
    const int csel = (((lane >> 4) ^ swq)) * 8;       // swizzled LDS col
    const int rowa = wr + (lane & 15);
    const int rowb = wc + (lane & 15);

    for (int kt = 0; kt < 32; ++kt) {
        const int k0 = kt * 32;
        async16(xb + (size_t)(m0 + r0) * D_ + k0 + sc, &As[t * 8]);
        async16(xb + (size_t)(m0 + r1) * D_ + k0 + sc, &As[(t + 256) * 8]);
        async16(W0 + (size_t)r0 * D_ + k0 + sc, &B0[t * 8]);
        async16(W0 + (size_t)r1 * D_ + k0 + sc, &B0[(t + 256) * 8]);
        async16(W1 + (size_t)r0 * D_ + k0 + sc, &B1[t * 8]);
        async16(W1 + (size_t)r1 * D_ + k0 + sc, &B1[(t + 256) * 8]);
        __syncthreads();

        bf16x8 af[4], b08[4], b18[4];
#pragma unroll
        for (int i = 0; i < 4; ++i)
            af[i] = *(const bf16x8*)&As[(rowa + i * 16) * 32 + csel];
#pragma unroll
        for (int j = 0; j < 4; ++j) {
            b08[j] = *(const bf16x8*)&B0[(rowb + j * 16) * 32 + csel];
            b18[j] = *(const bf16x8*)&B1[(rowb + j * 16) * 32 + csel];
        }
#pragma unroll
        for (int i = 0; i < 4; ++i)
#pragma unroll
            for (int j = 0; j < 4; ++j) {
                acc0[i][j] = __builtin_amdgcn_mfma_f32_16x16x32_bf16(
                    af[i], b08[j], acc0[i][j], 0, 0, 0);
                acc1[i][j] = __builtin_amdgcn_mfma_f32_16x16x32_bf16(
                    af[i], b18[j], acc1[i][j], 0, 0, 0);
            }
        __syncthreads();
    }

    // epilogue: C/D layout col=lane&15, row=(lane>>4)*4+r
    const int colq = lane & 15;
    const int quad = lane >> 4;
    const int rowq = quad * 4;

    if (qmode) {
        const float* bias0 = bq + n0;
        const float* bias1 = bq + n0 + 128;
#pragma unroll
        for (int i = 0; i < 4; ++i) {
#pragma unroll
            for (int j = 0; j < 4; ++j) {
                const int c = wc + j * 16 + colq;
                const float bv0 = bias0[c], bv1 = bias1[c];
#pragma unroll
                for (int r = 0; r < 4; ++r) {
                    const int rg = m0 + wr + i * 16 + rowq + r;
                    qb[(size_t)rg * D_ + n0 + c]       = f2bf(acc0[i][j][r] + bv0);
                    qb[(size_t)rg * D_ + n0 + 128 + c] = f2bf(acc1[i][j][r] + bv1);
                }
            }
        }
    } else {
        // kv-mode: store kvb and accumulate chunk sums.
        // weight(localrow) = dec^(31 - 16*(i&1) - 4*quad - r)
        //   i&1==0: dec^(4*(7-quad) + (3-r)) = P0 * dec^(3-r)
        //   i&1==1: dec^(4*(3-quad) + (3-r)) = P1 * dec^(3-r)
        const float* bias0 = bk + n0;
        const float* bias1 = bv + n0;
        const int bidx = m0 >> 11;            // batch
        const int cbase = ((m0 & 2047) >> 5) + (wr >> 5);  // global chunk of this wave's first 32 rows
        float s0[4], s1[4];                   // chunk sums: rows wr..wr+31, wr+32..wr+63
#pragma unroll
        for (int j = 0; j < 4; ++j) { s0[j] = 0.f; s1[j] = 0.f; }

#pragma unroll
        for (int j = 0; j < 4; ++j) {
            const int c = wc + j * 16 + colq;
            const float bv0 = bias0[c], bv1 = bias1[c];
            const float dec = decay[n0 + c];
            const float d2 = dec * dec, d4 = d2 * d2;
            const float d8 = d4 * d4, d16 = d8 * d8;
            const float d3 = d2 * dec;
            const float d4p3 = d8 * d4;
            const float P1 = (quad == 0) ? d4p3 : ((quad == 1) ? d8 : ((quad == 2) ? d4 : 1.0f));
            const float P0 = d16 * P1;
            const float wr3[4] = {d3, d2, dec, 1.0f};   // dec^(3-r)
#pragma unroll
            for (int i = 0; i < 4; ++i) {
                const float base_w = (i & 1) ? P1 : P0;
#pragma unroll
                for (int r = 0; r < 4; ++r) {
                    const int rg = m0 + wr + i * 16 + rowq + r;
                    const float kf = acc0[i][j][r] + bv0;
                    const float vf = acc1[i][j][r] + bv1;
                    const float kvf = kf * vf;
                    kvb[(size_t)rg * D_ + n0 + c] = f2bf(kvf);
                    const float wgt = base_w * wr3[r];
                    if (i < 2) s0[j] = fmaf(kvf, wgt, s0[j]);
                    else       s1[j] = fmaf(kvf, wgt, s1[j]);
                }
            }
        }
        // quad-reduction: lanes {l, l+16, l+32, l+48} hold same column
#pragma unroll
        for (int j = 0; j < 4; ++j) {
            s0[j] += __shfl_xor(s0[j], 16, 64);
            s0[j] += __shfl_xor(s0[j], 32, 64);
            s1[j] += __shfl_xor(s1[j], 16, 64);
            s1[j] += __shfl_xor(s1[j], 32, 64);
        }
        if (quad == 0) {
#pragma unroll
            for (int j = 0; j < 4; ++j) {
                const int cg = n0 + wc + j * 16 + colq;
                S[(((size_t)bidx * NCHUNK) + cbase) * D_ + cg]     = s0[j];
                S[(((size_t)bidx * NCHUNK) + cbase + 1) * D_ + cg] = s1[j];
            }
        }
    }
}

// ------- scan final: redundant carry-Horner over S, replay, out = q*mem -------
// grid = B_*NCHUNK = 512 blocks; 256 threads x 4 channels.
__global__ __launch_bounds__(256) void scan_final2(
    const ushort_t* __restrict__ kvb, const ushort_t* __restrict__ qb,
    const float* __restrict__ decay, const float* __restrict__ S,
    float* __restrict__ out) {
    const int b = blockIdx.x >> 6;
    const int c = blockIdx.x & 63;
    const int d0 = threadIdx.x * 4;
    const float4 dc = *(const float4*)&decay[d0];
    // dec^32 per channel (5 squarings)
    float e0 = dc.x, e1 = dc.y, e2 = dc.z, e3 = dc.w;
#pragma unroll
    for (int s = 0; s < 5; ++s) { e0 *= e0; e1 *= e1; e2 *= e2; e3 *= e3; }
    // carry: P = sum_{cc<c} dL^(c-1-cc) S[cc]  (Horner; S is 2MB, L2-hot)
    float m0 = 0.f, m1 = 0.f, m2 = 0.f, m3 = 0.f;
    const float* Sb = &S[((size_t)b * NCHUNK) * D_ + d0];
    for (int cc = 0; cc < c; ++cc) {
        float4 s4 = *(const float4*)&Sb[(size_t)cc * D_];
        m0 = fmaf(e0, m0, s4.x);
        m1 = fmaf(e1, m1, s4.y);
        m2 = fmaf(e2, m2, s4.z);
        m3 = fmaf(e3, m3, s4.w);
    }
    // replay chunk with carry
    size_t base = ((size_t)b * T_ + c * CHUNKLEN) * D_ + d0;
#pragma unroll 8
    for (int i = 0; i < CHUNKLEN; ++i) {
        const size_t o = base + (size_t)i * D_;
        ushort4 kv = *(const ushort4*)&kvb[o];
        ushort4 q4 = *(const ushort4*)&qb[o];
        m0 = fmaf(dc.x, m0, bf2f(kv.x));
        m1 = fmaf(dc.y, m1, bf2f(kv.y));
        m2 = fmaf(dc.z, m2, bf2f(kv.z));
        m3 = fmaf(dc.w, m3, bf2f(kv.w));
        *(float4*)&out[o] = make_float4(bf2f(q4.x) * m0, bf2f(q4.y) * m1,
                                        bf2f(q4.z) * m2, bf2f(q4.w) * m3);
    }
}

extern "C" void kernel_launch(void* const* d_in, const int* in_sizes, int n_in,
                              void* d_out, int out_size, void* d_ws, size_t ws_size,
                              hipStream_t stream) {
    const float* x     = (const float*)d_in[0];
    const float* Wq    = (const float*)d_in[1];
    const float* bq    = (const float*)d_in[2];
    const float* Wk    = (const float*)d_in[3];
    const float* bk    = (const float*)d_in[4];
    const float* Wv    = (const float*)d_in[5];
    const float* bv    = (const float*)d_in[6];
    const float* decay = (const float*)d_in[7];
    float* out = (float*)d_out;

    // workspace carve (~109 MB). S no longer aliases xb (written during GEMM).
    char* ws = (char*)d_ws;
    ushort_t* xb  = (ushort_t*)(ws);                        // 33,554,432 B
    ushort_t* Wb  = (ushort_t*)(ws + 33554432);             //  6,291,456 B
    ushort_t* qb  = (ushort_t*)(ws + 39845888);             // 33,554,432 B
    ushort_t* kvb = (ushort_t*)(ws + 73400320);             // 33,554,432 B
    float*    S   = (float*)(ws + 106954752);               //  2,097,152 B

    ushort_t* Wqb = Wb;
    ushort_t* Wkb = Wb + D_ * D_;
    ushort_t* Wvb = Wb + 2 * D_ * D_;

    const int ncast = (M_ * D_ / 4) + (3 * D_ * D_ / 4);
    cast_all<<<ncast / 256, 256, 0, stream>>>(x, Wq, Wk, Wv, xb, Wb);

    gemm_qkv<<<1536, 256, 0, stream>>>(xb, Wqb, Wkb, Wvb, bq, bk, bv, decay,
                                       qb, kvb, S);

    scan_final2<<<B_ * NCHUNK, 256, 0, stream>>>(kvb, qb, decay, S, out);
}

// Round 6
// 248.094 us; speedup vs baseline: 1.1252x; 1.0992x over previous
//
#include <hip/hip_runtime.h>
#include <cstdint>

typedef unsigned short ushort_t;
typedef __bf16 bf16x8 __attribute__((ext_vector_type(8)));
typedef float f32x4 __attribute__((ext_vector_type(4)));

#define B_ 8
#define T_ 2048
#define D_ 1024
#define M_ (B_ * T_)        // 16384
#define NCHUNK 64
#define CHUNKLEN 32         // 64*32 = 2048 = T_

__device__ __forceinline__ ushort_t f2bf(float f) {
    union { float f; uint32_t u; } v; v.f = f;
    uint32_t u = v.u;
    uint32_t r = (u + 0x7fffu + ((u >> 16) & 1u)) >> 16;
    return (ushort_t)r;
}
__device__ __forceinline__ float bf2f(ushort_t h) {
    union { uint32_t u; float f; } v; v.u = ((uint32_t)h) << 16;
    return v.f;
}

__device__ __forceinline__ void async16(const ushort_t* g, ushort_t* l) {
    __builtin_amdgcn_global_load_lds(
        (const __attribute__((address_space(1))) void*)g,
        (__attribute__((address_space(3))) void*)l, 16, 0, 0);
}

// ---------------- one-shot cast: x + Wq + Wk + Wv -> bf16 ----------------
__global__ __launch_bounds__(256) void cast_all(
    const float* __restrict__ x, const float* __restrict__ wq,
    const float* __restrict__ wk, const float* __restrict__ wv,
    ushort_t* __restrict__ xb, ushort_t* __restrict__ Wb) {
    const int nx4 = M_ * D_ / 4, nw4 = D_ * D_ / 4;
    int i = blockIdx.x * blockDim.x + threadIdx.x;
    const float* src; ushort_t* dstp; int si;
    if (i < nx4) {
        src = x; si = i; dstp = xb + (size_t)i * 4;
    } else {
        int j = i - nx4;
        dstp = Wb + (size_t)j * 4;
        if (j < nw4)          { src = wq; si = j; }
        else if (j < 2 * nw4) { src = wk; si = j - nw4; }
        else                  { src = wv; si = j - 2 * nw4; }
    }
    float4 v = ((const float4*)src)[si];
    ushort4 o;
    o.x = f2bf(v.x); o.y = f2bf(v.y); o.z = f2bf(v.z); o.w = f2bf(v.w);
    *(ushort4*)dstp = o;
}

// ============ Unified QKV GEMM (BK=64) + fused chunk-scan ============
// LDS tiles 128 rows x 64 cols bf16 (16 KB each). Row = 8 chunks of 16 B.
// Swizzle: LDS slot s of row r holds global chunk g = s ^ (r & 7); reader
// fetches logical chunk lc at slot lc ^ (r & 7). ds_read_b128 by a quad
// (16 consecutive rows, same lc) then spans all 8 bank-groups -> 2-way (free).
// blocks [0,512):   q-mode:  qb = x@Wq^T+bq (bf16), n-tile 256
// blocks [512,1536): kv-mode: kvb = (x@Wk^T+bk)*(x@Wv^T+bv) (bf16), n-tile 128,
//   plus chunk sums S[b,c,d] = sum_tau dec^(31-tau) kv[32c+tau,d] via registers.
__global__ __launch_bounds__(256, 2) void gemm_qkv(
    const ushort_t* __restrict__ xb, const ushort_t* __restrict__ Wq,
    const ushort_t* __restrict__ Wk, const ushort_t* __restrict__ Wv,
    const float* __restrict__ bq, const float* __restrict__ bk,
    const float* __restrict__ bv, const float* __restrict__ decay,
    ushort_t* __restrict__ qb, ushort_t* __restrict__ kvb,
    float* __restrict__ S) {
    __shared__ ushort_t As[128 * 64];
    __shared__ ushort_t B0[128 * 64];
    __shared__ ushort_t B1[128 * 64];

    const int idx = blockIdx.x;
    const bool qmode = idx < 512;
    int mb, n0;
    const ushort_t *W0, *W1;
    if (qmode) {
        mb = idx & 127; n0 = (idx >> 7) * 256;
        W0 = Wq + (size_t)n0 * D_;
        W1 = Wq + (size_t)(n0 + 128) * D_;
    } else {
        const int j = idx - 512;
        mb = j & 127; n0 = (j >> 7) * 128;
        W0 = Wk + (size_t)n0 * D_;
        W1 = Wv + (size_t)n0 * D_;
    }
    const int m0 = mb * 128;

    const int t = threadIdx.x;
    const int lane = t & 63, wv = t >> 6;
    const int wr = (wv >> 1) * 64, wc = (wv & 1) * 64;

    f32x4 acc0[4][4], acc1[4][4];
#pragma unroll
    for (int i = 0; i < 4; ++i)
#pragma unroll
        for (int j = 0; j < 4; ++j) {
            acc0[i][j] = (f32x4){0.f, 0.f, 0.f, 0.f};
            acc1[i][j] = (f32x4){0.f, 0.f, 0.f, 0.f};
        }

    // staging: thread t covers rows rs+{0,32,64,96}, slot t&7, per 16 KB tile
    const int rs = t >> 3;                       // base row 0..31
    const int g = (t & 7) ^ (rs & 7);            // swizzled source chunk
    const int scol = g * 8;                      // source element col in 64-slice

    // read-side swizzled columns (same for A and B: wr,wc are multiples of 8)
    const int quad = lane >> 4;
    const int l7 = lane & 7;
    const int cs0 = ((quad) ^ l7) * 8;           // k-half 0
    const int cs1 = ((4 + quad) ^ l7) * 8;       // k-half 1
    const int rowa = wr + (lane & 15);
    const int rowb = wc + (lane & 15);

    for (int kt = 0; kt < 16; ++kt) {
        const int k0 = kt * 64;
#pragma unroll
        for (int p = 0; p < 4; ++p) {
            const int rp = rs + p * 32;
            const int Lofs = (t + p * 256) * 8;
            async16(xb + (size_t)(m0 + rp) * D_ + k0 + scol, &As[Lofs]);
            async16(W0 + (size_t)rp * D_ + k0 + scol, &B0[Lofs]);
            async16(W1 + (size_t)rp * D_ + k0 + scol, &B1[Lofs]);
        }
        __syncthreads();

#pragma unroll
        for (int h = 0; h < 2; ++h) {
            const int cs = h ? cs1 : cs0;
            bf16x8 af[4], b08[4], b18[4];
#pragma unroll
            for (int i = 0; i < 4; ++i)
                af[i] = *(const bf16x8*)&As[(rowa + i * 16) * 64 + cs];
#pragma unroll
            for (int j = 0; j < 4; ++j) {
                b08[j] = *(const bf16x8*)&B0[(rowb + j * 16) * 64 + cs];
                b18[j] = *(const bf16x8*)&B1[(rowb + j * 16) * 64 + cs];
            }
#pragma unroll
            for (int i = 0; i < 4; ++i)
#pragma unroll
                for (int j = 0; j < 4; ++j) {
                    acc0[i][j] = __builtin_amdgcn_mfma_f32_16x16x32_bf16(
                        af[i], b08[j], acc0[i][j], 0, 0, 0);
                    acc1[i][j] = __builtin_amdgcn_mfma_f32_16x16x32_bf16(
                        af[i], b18[j], acc1[i][j], 0, 0, 0);
                }
        }
        __syncthreads();
    }

    // epilogue: C/D layout col=lane&15, row=quad*4+r
    const int colq = lane & 15;
    const int rowq = quad * 4;

    if (qmode) {
        const float* bias0 = bq + n0;
        const float* bias1 = bq + n0 + 128;
#pragma unroll
        for (int i = 0; i < 4; ++i) {
#pragma unroll
            for (int j = 0; j < 4; ++j) {
                const int c = wc + j * 16 + colq;
                const float bv0 = bias0[c], bv1 = bias1[c];
#pragma unroll
                for (int r = 0; r < 4; ++r) {
                    const int rg = m0 + wr + i * 16 + rowq + r;
                    qb[(size_t)rg * D_ + n0 + c]       = f2bf(acc0[i][j][r] + bv0);
                    qb[(size_t)rg * D_ + n0 + 128 + c] = f2bf(acc1[i][j][r] + bv1);
                }
            }
        }
    } else {
        // kv-mode, row-outer store order (full 128B row segments -> no partial
        // line writeback). weight(localrow) = dec^(31-16(i&1)-4*quad-r).
        const float* bias0 = bk + n0;
        const float* bias1 = bv + n0;
        const int bidx = m0 >> 11;
        const int cbase = ((m0 & 2047) >> 5) + (wr >> 5);
        int cj[4];
        float bv0a[4], bv1a[4], d1a[4], d2a[4], d3a[4], P0a[4], P1a[4];
#pragma unroll
        for (int j = 0; j < 4; ++j) {
            const int c = wc + j * 16 + colq;
            cj[j] = c;
            bv0a[j] = bias0[c];
            bv1a[j] = bias1[c];
            const float dec = decay[n0 + c];
            const float d2 = dec * dec, d4 = d2 * d2;
            const float d8 = d4 * d4, d16 = d8 * d8;
            d1a[j] = dec; d2a[j] = d2; d3a[j] = d2 * dec;
            const float P1 = (quad == 0) ? (d8 * d4) : ((quad == 1) ? d8 : ((quad == 2) ? d4 : 1.0f));
            P1a[j] = P1;
            P0a[j] = d16 * P1;
        }
        float s0[4], s1[4];
#pragma unroll
        for (int j = 0; j < 4; ++j) { s0[j] = 0.f; s1[j] = 0.f; }

#pragma unroll
        for (int i = 0; i < 4; ++i) {
#pragma unroll
            for (int r = 0; r < 4; ++r) {
                const int rg = m0 + wr + i * 16 + rowq + r;
                ushort_t* rowp = kvb + (size_t)rg * D_ + n0;
#pragma unroll
                for (int j = 0; j < 4; ++j) {
                    const float kf = acc0[i][j][r] + bv0a[j];
                    const float vf = acc1[i][j][r] + bv1a[j];
                    const float kvf = kf * vf;
                    rowp[cj[j]] = f2bf(kvf);
                    const float w3 = (r == 0) ? d3a[j] : ((r == 1) ? d2a[j] : ((r == 2) ? d1a[j] : 1.0f));
                    const float wgt = ((i & 1) ? P1a[j] : P0a[j]) * w3;
                    if (i < 2) s0[j] = fmaf(kvf, wgt, s0[j]);
                    else       s1[j] = fmaf(kvf, wgt, s1[j]);
                }
            }
        }
#pragma unroll
        for (int j = 0; j < 4; ++j) {
            s0[j] += __shfl_xor(s0[j], 16, 64);
            s0[j] += __shfl_xor(s0[j], 32, 64);
            s1[j] += __shfl_xor(s1[j], 16, 64);
            s1[j] += __shfl_xor(s1[j], 32, 64);
        }
        if (quad == 0) {
#pragma unroll
            for (int j = 0; j < 4; ++j) {
                const int cg = n0 + cj[j];
                S[(((size_t)bidx * NCHUNK) + cbase) * D_ + cg]     = s0[j];
                S[(((size_t)bidx * NCHUNK) + cbase + 1) * D_ + cg] = s1[j];
            }
        }
    }
}

// ------- scan final: redundant carry-Horner over S, replay, out = q*mem -------
__global__ __launch_bounds__(256) void scan_final2(
    const ushort_t* __restrict__ kvb, const ushort_t* __restrict__ qb,
    const float* __restrict__ decay, const float* __restrict__ S,
    float* __restrict__ out) {
    const int b = blockIdx.x >> 6;
    const int c = blockIdx.x & 63;
    const int d0 = threadIdx.x * 4;
    const float4 dc = *(const float4*)&decay[d0];
    float e0 = dc.x, e1 = dc.y, e2 = dc.z, e3 = dc.w;
#pragma unroll
    for (int s = 0; s < 5; ++s) { e0 *= e0; e1 *= e1; e2 *= e2; e3 *= e3; }
    float m0 = 0.f, m1 = 0.f, m2 = 0.f, m3 = 0.f;
    const float* Sb = &S[((size_t)b * NCHUNK) * D_ + d0];
    for (int cc = 0; cc < c; ++cc) {
        float4 s4 = *(const float4*)&Sb[(size_t)cc * D_];
        m0 = fmaf(e0, m0, s4.x);
        m1 = fmaf(e1, m1, s4.y);
        m2 = fmaf(e2, m2, s4.z);
        m3 = fmaf(e3, m3, s4.w);
    }
    size_t base = ((size_t)b * T_ + c * CHUNKLEN) * D_ + d0;
#pragma unroll 8
    for (int i = 0; i < CHUNKLEN; ++i) {
        const size_t o = base + (size_t)i * D_;
        ushort4 kv = *(const ushort4*)&kvb[o];
        ushort4 q4 = *(const ushort4*)&qb[o];
        m0 = fmaf(dc.x, m0, bf2f(kv.x));
        m1 = fmaf(dc.y, m1, bf2f(kv.y));
        m2 = fmaf(dc.z, m2, bf2f(kv.z));
        m3 = fmaf(dc.w, m3, bf2f(kv.w));
        *(float4*)&out[o] = make_float4(bf2f(q4.x) * m0, bf2f(q4.y) * m1,
                                        bf2f(q4.z) * m2, bf2f(q4.w) * m3);
    }
}

extern "C" void kernel_launch(void* const* d_in, const int* in_sizes, int n_in,
                              void* d_out, int out_size, void* d_ws, size_t ws_size,
                              hipStream_t stream) {
    const float* x     = (const float*)d_in[0];
    const float* Wq    = (const float*)d_in[1];
    const float* bq    = (const float*)d_in[2];
    const float* Wk    = (const float*)d_in[3];
    const float* bk    = (const float*)d_in[4];
    const float* Wv    = (const float*)d_in[5];
    const float* bv    = (const float*)d_in[6];
    const float* decay = (const float*)d_in[7];
    float* out = (float*)d_out;

    char* ws = (char*)d_ws;
    ushort_t* xb  = (ushort_t*)(ws);                        // 33,554,432 B
    ushort_t* Wb  = (ushort_t*)(ws + 33554432);             //  6,291,456 B
    ushort_t* qb  = (ushort_t*)(ws + 39845888);             // 33,554,432 B
    ushort_t* kvb = (ushort_t*)(ws + 73400320);             // 33,554,432 B
    float*    S   = (float*)(ws + 106954752);               //  2,097,152 B

    ushort_t* Wqb = Wb;
    ushort_t* Wkb = Wb + D_ * D_;
    ushort_t* Wvb = Wb + 2 * D_ * D_;

    const int ncast = (M_ * D_ / 4) + (3 * D_ * D_ / 4);
    cast_all<<<ncast / 256, 256, 0, stream>>>(x, Wq, Wk, Wv, xb, Wb);

    gemm_qkv<<<1536, 256, 0, stream>>>(xb, Wqb, Wkb, Wvb, bq, bk, bv, decay,
                                       qb, kvb, S);

    scan_final2<<<B_ * NCHUNK, 256, 0, stream>>>(kvb, qb, decay, S, out);
}